// Round 6
// baseline (404.869 us; speedup 1.0000x reference)
//
#include <hip/hip_runtime.h>

#define NB 8
#define NC 512
#define NL 2048
#define NH 8
#define ND 64
#define NHID 512

typedef float f32x4 __attribute__((ext_vector_type(4)));
typedef short bf16x8 __attribute__((ext_vector_type(8)));
typedef unsigned uint32x2 __attribute__((ext_vector_type(2)));
typedef unsigned uint32x4 __attribute__((ext_vector_type(4)));

__device__ __forceinline__ unsigned short f2bf(float x) {
    unsigned u = __float_as_uint(x);
    u += 0x7fffu + ((u >> 16) & 1u);
    return (unsigned short)(u >> 16);
}

__device__ __forceinline__ unsigned pack_bf16_ru(float lo, float hi) {
    unsigned a = __float_as_uint(lo) + 0x8000u;
    unsigned b = __float_as_uint(hi) + 0x8000u;
#if __has_builtin(__builtin_amdgcn_perm)
    return __builtin_amdgcn_perm(b, a, 0x07060302u);
#else
    return (a >> 16) | (b & 0xffff0000u);
#endif
}

__device__ __forceinline__ float fexp2(float x) {
#if __has_builtin(__builtin_amdgcn_exp2f)
    return __builtin_amdgcn_exp2f(x);
#else
    return exp2f(x);
#endif
}

// C/D-layout -> B-frag relayout (register-only transpose across quads)
__device__ __forceinline__ void pfr_quad_swap(unsigned &a, unsigned &b) {
#if __has_builtin(__builtin_amdgcn_permlane32_swap) && __has_builtin(__builtin_amdgcn_permlane16_swap)
    uint32x2 r0 = __builtin_amdgcn_permlane32_swap(a, b, false, false);
    uint32x2 r1 = __builtin_amdgcn_permlane16_swap(r0[0], r0[1], false, false);
    a = r1[0];
    b = r1[1];
#else
    const int lane = (int)(threadIdx.x & 63);
    const int li = lane & 15, quad = lane >> 4;
    const int s0 = (li + ((quad & 1) << 5)) << 2;
    const int s1 = (li + 16 + ((quad & 1) << 5)) << 2;
    int ra = __builtin_amdgcn_ds_bpermute(s0, (int)a);
    int rb = __builtin_amdgcn_ds_bpermute(s0, (int)b);
    int ta = __builtin_amdgcn_ds_bpermute(s1, (int)a);
    int tb = __builtin_amdgcn_ds_bpermute(s1, (int)b);
    const bool lo = quad < 2;
    a = (unsigned)(lo ? ra : rb);
    b = (unsigned)(lo ? ta : tb);
#endif
}

// ---------------------------------------------------------------------------
// Kernel 1: QKV projection with register-prefetch software pipeline.
// ---------------------------------------------------------------------------
__global__ __launch_bounds__(256) void qkv_proj_kernel(
    const float* __restrict__ x, const float* __restrict__ w,
    unsigned short* __restrict__ qb, unsigned short* __restrict__ kb,
    unsigned short* __restrict__ vb)
{
    __shared__ __align__(16) unsigned short XT[128 * 40];
    __shared__ __align__(16) unsigned short WT[128 * 40];
    const int tid = threadIdx.x;
    const int wave = tid >> 6, lane = tid & 63;
    const int quad = lane >> 4, li = lane & 15;
    const int o0 = blockIdx.x * 128, l0 = blockIdx.y * 128, b = blockIdx.z;

    const f32x4 fzero = {0.f, 0.f, 0.f, 0.f};
    f32x4 acc[2][8];
    #pragma unroll
    for (int mt = 0; mt < 2; mt++)
        #pragma unroll
        for (int nt = 0; nt < 8; nt++) acc[mt][nt] = fzero;

    const int xl = tid & 127, xg = tid >> 7;
    const int wcg = tid & 7, woo = tid >> 3;

    float xv[2][8];
    float4 wv[4];
    #pragma unroll
    for (int i = 0; i < 2; i++) {
        const int cch = xg + 2 * i;
        const float* xs = x + ((size_t)(b * NC + cch * 8)) * NL + l0 + xl;
        #pragma unroll
        for (int k = 0; k < 8; k++) xv[i][k] = xs[(size_t)k * NL];
    }
    #pragma unroll
    for (int rep = 0; rep < 4; rep++)
        wv[rep] = *(const float4*)&w[(size_t)(o0 + woo + rep * 32) * NC + wcg * 4];

    for (int c0 = 0; c0 < NC; c0 += 32) {
        #pragma unroll
        for (int i = 0; i < 2; i++) {
            const int cch = xg + 2 * i;
            unsigned p[4];
            #pragma unroll
            for (int k2 = 0; k2 < 4; k2++)
                p[k2] = (unsigned)f2bf(xv[i][2 * k2]) |
                        ((unsigned)f2bf(xv[i][2 * k2 + 1]) << 16);
            uint4 val; val.x = p[0]; val.y = p[1]; val.z = p[2]; val.w = p[3];
            *(uint4*)&XT[xl * 40 + cch * 8] = val;
        }
        #pragma unroll
        for (int rep = 0; rep < 4; rep++) {
            uint2 val;
            val.x = (unsigned)f2bf(wv[rep].x) | ((unsigned)f2bf(wv[rep].y) << 16);
            val.y = (unsigned)f2bf(wv[rep].z) | ((unsigned)f2bf(wv[rep].w) << 16);
            *(uint2*)&WT[(woo + rep * 32) * 40 + wcg * 4] = val;
        }
        __syncthreads();
        if (c0 + 32 < NC) {
            const int c1 = c0 + 32;
            #pragma unroll
            for (int i = 0; i < 2; i++) {
                const int cch = xg + 2 * i;
                const float* xs = x + ((size_t)(b * NC + c1 + cch * 8)) * NL + l0 + xl;
                #pragma unroll
                for (int k = 0; k < 8; k++) xv[i][k] = xs[(size_t)k * NL];
            }
            #pragma unroll
            for (int rep = 0; rep < 4; rep++)
                wv[rep] = *(const float4*)&w[(size_t)(o0 + woo + rep * 32) * NC + c1 + wcg * 4];
        }
        bf16x8 afr0 = *(const bf16x8*)&XT[(wave * 32 + li) * 40 + quad * 8];
        bf16x8 afr1 = *(const bf16x8*)&XT[(wave * 32 + 16 + li) * 40 + quad * 8];
        #pragma unroll
        for (int nt = 0; nt < 8; nt++) {
            bf16x8 bfr = *(const bf16x8*)&WT[(nt * 16 + li) * 40 + quad * 8];
            acc[0][nt] = __builtin_amdgcn_mfma_f32_16x16x32_bf16(afr0, bfr, acc[0][nt], 0, 0, 0);
            acc[1][nt] = __builtin_amdgcn_mfma_f32_16x16x32_bf16(afr1, bfr, acc[1][nt], 0, 0, 0);
        }
        __syncthreads();
    }

    const int lr0 = l0 + wave * 32;
    if (o0 < 1024) {
        unsigned short* dst = (o0 < 512) ? qb : kb;
        const float scale = (o0 < 512) ? (0.125f * 1.44269504088896f) : 1.0f;
        #pragma unroll
        for (int mt = 0; mt < 2; mt++)
            #pragma unroll
            for (int nt = 0; nt < 8; nt++) {
                int oc = (o0 & 511) + nt * 16 + li;
                int hh = oc >> 6, d = oc & 63;
                size_t base =
                    ((size_t)((b * NH + hh) * NL) + lr0 + mt * 16 + quad * 4) * ND + d;
                #pragma unroll
                for (int r = 0; r < 4; r++)
                    dst[base + (size_t)r * ND] = f2bf(acc[mt][nt][r] * scale);
            }
    } else {
        #pragma unroll
        for (int mt = 0; mt < 2; mt++)
            #pragma unroll
            for (int nt = 0; nt < 8; nt++) {
                int oc = (o0 - 1024) + nt * 16 + li;
                int hh = oc >> 6, d = oc & 63;
                size_t base = ((size_t)((b * NH + hh) * ND) + d) * NL +
                              lr0 + mt * 16 + quad * 4;
                uint2 pv;
                pv.x = (unsigned)f2bf(acc[mt][nt][0]) | ((unsigned)f2bf(acc[mt][nt][1]) << 16);
                pv.y = (unsigned)f2bf(acc[mt][nt][2]) | ((unsigned)f2bf(acc[mt][nt][3]) << 16);
                *(uint2*)&vb[base] = pv;
            }
    }
}

// ---------------------------------------------------------------------------
// Kernel 2: flash attention, j-CHUNKED dataflow to cap register pressure.
// Per 32-j chunk: S^T (16 regs) -> exp2/pack (8 regs) -> PV MFMAs, so the
// 64-reg st / 32-reg pk monoliths of R3-R5 never exist.  Prefetch for tile
// kt+1 held in NAMED uint4 scalars (SROA-trivial; R4/R5 lesson: array-typed
// prefetch got spilled to scratch -> ~470MB writes).  Peak live ~115 VGPR,
// __launch_bounds__(256,4) pins the 128-cap / 4 blocks/CU target.
// ---------------------------------------------------------------------------
__global__ __launch_bounds__(256, 4) void attn_kernel(
    const unsigned short* __restrict__ qb, const unsigned short* __restrict__ kb,
    const unsigned short* __restrict__ vb, unsigned short* __restrict__ at)
{
    __shared__ __align__(16) unsigned short Kt[128 * 72];  // [j][d], pad 64->72
    __shared__ __align__(16) unsigned short Vt[64 * 136];  // [d][j], pad 128->136
    const int tid = threadIdx.x;
    const int wave = tid >> 6, lane = tid & 63;
    const int quad = lane >> 4, li = lane & 15;
    const int qt = blockIdx.x, h = blockIdx.y, b = blockIdx.z;
    const int bh = b * NH + h;
    const unsigned short* Qb = qb + (size_t)bh * NL * ND;
    const unsigned short* Kb = kb + (size_t)bh * NL * ND;
    const unsigned short* Vb = vb + (size_t)bh * ND * NL;

    bf16x8 qfr[2][2];
    #pragma unroll
    for (int mt = 0; mt < 2; mt++)
        #pragma unroll
        for (int kc = 0; kc < 2; kc++)
            qfr[mt][kc] = *(const bf16x8*)&Qb[(size_t)(qt * 128 + wave * 32 + mt * 16 + li) * ND +
                                             kc * 32 + quad * 8];

    const f32x4 fzero = {0.f, 0.f, 0.f, 0.f};
    float lsum0 = 0.f, lsum1 = 0.f;
    f32x4 oacc[2][4];
    #pragma unroll
    for (int mt = 0; mt < 2; mt++)
        #pragma unroll
        for (int dt = 0; dt < 4; dt++) oacc[mt][dt] = fzero;

    const int kch = tid & 7, kjj = tid >> 3;
    const int vch = tid & 15, vdd = tid >> 4;

    // lane-constant base pointers for staging
    const unsigned short* kbase = Kb + (size_t)kjj * ND + kch * 8;
    const unsigned short* vbase = Vb + (size_t)vdd * NL + vch * 8;

    // prefetch tile 0 into named scalars
    uint4 k0 = *(const uint4*)(kbase + (size_t)0 * 32 * ND);
    uint4 k1 = *(const uint4*)(kbase + (size_t)1 * 32 * ND);
    uint4 k2 = *(const uint4*)(kbase + (size_t)2 * 32 * ND);
    uint4 k3 = *(const uint4*)(kbase + (size_t)3 * 32 * ND);
    uint4 v0 = *(const uint4*)(vbase + (size_t)0 * 16 * NL);
    uint4 v1 = *(const uint4*)(vbase + (size_t)1 * 16 * NL);
    uint4 v2 = *(const uint4*)(vbase + (size_t)2 * 16 * NL);
    uint4 v3 = *(const uint4*)(vbase + (size_t)3 * 16 * NL);

    for (int kt = 0; kt < 16; kt++) {
        *(uint4*)&Kt[(kjj + 0 * 32) * 72 + kch * 8] = k0;
        *(uint4*)&Kt[(kjj + 1 * 32) * 72 + kch * 8] = k1;
        *(uint4*)&Kt[(kjj + 2 * 32) * 72 + kch * 8] = k2;
        *(uint4*)&Kt[(kjj + 3 * 32) * 72 + kch * 8] = k3;
        *(uint4*)&Vt[(vdd + 0 * 16) * 136 + vch * 8] = v0;
        *(uint4*)&Vt[(vdd + 1 * 16) * 136 + vch * 8] = v1;
        *(uint4*)&Vt[(vdd + 2 * 16) * 136 + vch * 8] = v2;
        *(uint4*)&Vt[(vdd + 3 * 16) * 136 + vch * 8] = v3;
        __syncthreads();
        if (kt < 15) {
            const size_t koff = (size_t)(kt + 1) * 128 * ND;
            const size_t voff = (size_t)(kt + 1) * 128;
            k0 = *(const uint4*)(kbase + koff + (size_t)0 * 32 * ND);
            k1 = *(const uint4*)(kbase + koff + (size_t)1 * 32 * ND);
            k2 = *(const uint4*)(kbase + koff + (size_t)2 * 32 * ND);
            k3 = *(const uint4*)(kbase + koff + (size_t)3 * 32 * ND);
            v0 = *(const uint4*)(vbase + voff + (size_t)0 * 16 * NL);
            v1 = *(const uint4*)(vbase + voff + (size_t)1 * 16 * NL);
            v2 = *(const uint4*)(vbase + voff + (size_t)2 * 16 * NL);
            v3 = *(const uint4*)(vbase + voff + (size_t)3 * 16 * NL);
        }

        // process 4 chunks of 32 j-columns each: S^T -> exp2/pack -> PV
        #pragma unroll
        for (int c = 0; c < 4; c++) {
            f32x4 st00 = fzero, st01 = fzero, st10 = fzero, st11 = fzero;
            #pragma unroll
            for (int dk = 0; dk < 2; dk++) {
                bf16x8 kf0 = *(const bf16x8*)&Kt[((2 * c + 0) * 16 + li) * 72 + dk * 32 + quad * 8];
                bf16x8 kf1 = *(const bf16x8*)&Kt[((2 * c + 1) * 16 + li) * 72 + dk * 32 + quad * 8];
                st00 = __builtin_amdgcn_mfma_f32_16x16x32_bf16(kf0, qfr[0][dk], st00, 0, 0, 0);
                st01 = __builtin_amdgcn_mfma_f32_16x16x32_bf16(kf1, qfr[0][dk], st01, 0, 0, 0);
                st10 = __builtin_amdgcn_mfma_f32_16x16x32_bf16(kf0, qfr[1][dk], st10, 0, 0, 0);
                st11 = __builtin_amdgcn_mfma_f32_16x16x32_bf16(kf1, qfr[1][dk], st11, 0, 0, 0);
            }

            // exp2 + row-sum + pack, per mt
            unsigned p000, p001, p010, p011, p100, p101, p110, p111;
            {
                float a0 = fexp2(st00[0]), a1 = fexp2(st00[1]),
                      a2 = fexp2(st00[2]), a3 = fexp2(st00[3]);
                float b0 = fexp2(st01[0]), b1 = fexp2(st01[1]),
                      b2 = fexp2(st01[2]), b3 = fexp2(st01[3]);
                lsum0 += (a0 + a1) + (a2 + a3) + (b0 + b1) + (b2 + b3);
                p000 = pack_bf16_ru(a0, a1); p001 = pack_bf16_ru(a2, a3);
                p010 = pack_bf16_ru(b0, b1); p011 = pack_bf16_ru(b2, b3);
            }
            {
                float a0 = fexp2(st10[0]), a1 = fexp2(st10[1]),
                      a2 = fexp2(st10[2]), a3 = fexp2(st10[3]);
                float b0 = fexp2(st11[0]), b1 = fexp2(st11[1]),
                      b2 = fexp2(st11[2]), b3 = fexp2(st11[3]);
                lsum1 += (a0 + a1) + (a2 + a3) + (b0 + b1) + (b2 + b3);
                p100 = pack_bf16_ru(a0, a1); p101 = pack_bf16_ru(a2, a3);
                p110 = pack_bf16_ru(b0, b1); p111 = pack_bf16_ru(b2, b3);
            }

            // C/D -> B-frag relayout (cross-quad register transpose)
            pfr_quad_swap(p000, p010);
            pfr_quad_swap(p001, p011);
            pfr_quad_swap(p100, p110);
            pfr_quad_swap(p101, p111);

            uint32x4 u0 = {p000, p001, p010, p011};
            uint32x4 u1 = {p100, p101, p110, p111};
            bf16x8 pf0 = __builtin_bit_cast(bf16x8, u0);
            bf16x8 pf1 = __builtin_bit_cast(bf16x8, u1);

            // PV for this j-chunk
            #pragma unroll
            for (int dt = 0; dt < 4; dt++) {
                bf16x8 vfr = *(const bf16x8*)&Vt[(dt * 16 + li) * 136 + c * 32 + quad * 8];
                oacc[0][dt] = __builtin_amdgcn_mfma_f32_16x16x32_bf16(vfr, pf0, oacc[0][dt], 0, 0, 0);
                oacc[1][dt] = __builtin_amdgcn_mfma_f32_16x16x32_bf16(vfr, pf1, oacc[1][dt], 0, 0, 0);
            }
        }
        __syncthreads();
    }

    lsum0 += __shfl_xor(lsum0, 16, 64);
    lsum0 += __shfl_xor(lsum0, 32, 64);
    lsum1 += __shfl_xor(lsum1, 16, 64);
    lsum1 += __shfl_xor(lsum1, 32, 64);

    #pragma unroll
    for (int mt = 0; mt < 2; mt++) {
        const float rl = 1.0f / (mt ? lsum1 : lsum0);
        const int l = qt * 128 + wave * 32 + mt * 16 + li;
        #pragma unroll
        for (int dt = 0; dt < 4; dt++) {
            uint2 ov;
            ov.x = (unsigned)f2bf(oacc[mt][dt][0] * rl) |
                   ((unsigned)f2bf(oacc[mt][dt][1] * rl) << 16);
            ov.y = (unsigned)f2bf(oacc[mt][dt][2] * rl) |
                   ((unsigned)f2bf(oacc[mt][dt][3] * rl) << 16);
            *(uint2*)&at[((size_t)(b * NL + l)) * NHID + h * ND + dt * 16 + quad * 4] = ov;
        }
    }
}

// ---------------------------------------------------------------------------
// Kernel 3: output projection with register-prefetch software pipeline.
// ---------------------------------------------------------------------------
__global__ __launch_bounds__(256) void out_proj_kernel(
    const unsigned short* __restrict__ at, const float* __restrict__ w,
    const float* __restrict__ bias, float* __restrict__ out)
{
    __shared__ __align__(16) unsigned short Wl[128 * 40];
    __shared__ __align__(16) unsigned short Al[128 * 40];
    const int tid = threadIdx.x;
    const int wave = tid >> 6, lane = tid & 63;
    const int quad = lane >> 4, li = lane & 15;
    const int o0 = blockIdx.x * 128, l0 = blockIdx.y * 128, b = blockIdx.z;

    const f32x4 fzero = {0.f, 0.f, 0.f, 0.f};
    f32x4 acc[2][8];
    #pragma unroll
    for (int mt = 0; mt < 2; mt++)
        #pragma unroll
        for (int nt = 0; nt < 8; nt++) acc[mt][nt] = fzero;

    const int wcg = tid & 7, woo = tid >> 3;
    const int ach = tid & 3, al0 = tid >> 2;

    float4 wv[4];
    uint4 av[2];
    #pragma unroll
    for (int rep = 0; rep < 4; rep++)
        wv[rep] = *(const float4*)&w[(size_t)(o0 + woo + rep * 32) * NHID + wcg * 4];
    #pragma unroll
    for (int rep = 0; rep < 2; rep++)
        av[rep] = *(const uint4*)&at[(size_t)(b * NL + l0 + al0 + rep * 64) * NHID + ach * 8];

    for (int c0 = 0; c0 < NHID; c0 += 32) {
        #pragma unroll
        for (int rep = 0; rep < 4; rep++) {
            uint2 val;
            val.x = (unsigned)f2bf(wv[rep].x) | ((unsigned)f2bf(wv[rep].y) << 16);
            val.y = (unsigned)f2bf(wv[rep].z) | ((unsigned)f2bf(wv[rep].w) << 16);
            *(uint2*)&Wl[(woo + rep * 32) * 40 + wcg * 4] = val;
        }
        #pragma unroll
        for (int rep = 0; rep < 2; rep++)
            *(uint4*)&Al[(al0 + rep * 64) * 40 + ach * 8] = av[rep];
        __syncthreads();
        if (c0 + 32 < NHID) {
            const int c1 = c0 + 32;
            #pragma unroll
            for (int rep = 0; rep < 4; rep++)
                wv[rep] = *(const float4*)&w[(size_t)(o0 + woo + rep * 32) * NHID + c1 + wcg * 4];
            #pragma unroll
            for (int rep = 0; rep < 2; rep++)
                av[rep] = *(const uint4*)&at[(size_t)(b * NL + l0 + al0 + rep * 64) * NHID + c1 + ach * 8];
        }
        bf16x8 afr0 = *(const bf16x8*)&Wl[(wave * 32 + li) * 40 + quad * 8];
        bf16x8 afr1 = *(const bf16x8*)&Wl[(wave * 32 + 16 + li) * 40 + quad * 8];
        #pragma unroll
        for (int nt = 0; nt < 8; nt++) {
            bf16x8 bfr = *(const bf16x8*)&Al[(nt * 16 + li) * 40 + quad * 8];
            acc[0][nt] = __builtin_amdgcn_mfma_f32_16x16x32_bf16(afr0, bfr, acc[0][nt], 0, 0, 0);
            acc[1][nt] = __builtin_amdgcn_mfma_f32_16x16x32_bf16(afr1, bfr, acc[1][nt], 0, 0, 0);
        }
        __syncthreads();
    }

    #pragma unroll
    for (int mt = 0; mt < 2; mt++) {
        int or0 = o0 + wave * 32 + mt * 16 + quad * 4;
        #pragma unroll
        for (int nt = 0; nt < 8; nt++) {
            int l = l0 + nt * 16 + li;
            #pragma unroll
            for (int r = 0; r < 4; r++)
                out[((size_t)(b * NC + or0 + r)) * NL + l] = acc[mt][nt][r] + bias[or0 + r];
        }
    }
}

extern "C" void kernel_launch(void* const* d_in, const int* in_sizes, int n_in,
                              void* d_out, int out_size, void* d_ws, size_t ws_size,
                              hipStream_t stream) {
    const float* x = (const float*)d_in[0];
    const float* w_qkv = (const float*)d_in[1];
    const float* w_out = (const float*)d_in[2];
    const float* b_out = (const float*)d_in[3];
    float* out = (float*)d_out;

    unsigned short* ws = (unsigned short*)d_ws;
    const size_t SZ = (size_t)NB * NH * NL * ND;
    unsigned short* qb = ws;
    unsigned short* kb = qb + SZ;
    unsigned short* vb = kb + SZ;
    unsigned short* at = vb + SZ;

    qkv_proj_kernel<<<dim3(12, 16, 8), dim3(256), 0, stream>>>(x, w_qkv, qb, kb, vb);
    attn_kernel<<<dim3(16, 8, 8), dim3(256), 0, stream>>>(qb, kb, vb, at);
    out_proj_kernel<<<dim3(4, 16, 8), dim3(256), 0, stream>>>(at, w_out, b_out, out);
}

// Round 7
// 271.321 us; speedup vs baseline: 1.4922x; 1.4922x over previous
//
#include <hip/hip_runtime.h>

#define NB 8
#define NC 512
#define NL 2048
#define NH 8
#define ND 64
#define NHID 512

typedef float f32x4 __attribute__((ext_vector_type(4)));
typedef short bf16x8 __attribute__((ext_vector_type(8)));
typedef unsigned uint32x2 __attribute__((ext_vector_type(2)));
typedef unsigned uint32x4 __attribute__((ext_vector_type(4)));

__device__ __forceinline__ unsigned short f2bf(float x) {
    unsigned u = __float_as_uint(x);
    u += 0x7fffu + ((u >> 16) & 1u);
    return (unsigned short)(u >> 16);
}

__device__ __forceinline__ unsigned pack_bf16_ru(float lo, float hi) {
    unsigned a = __float_as_uint(lo) + 0x8000u;
    unsigned b = __float_as_uint(hi) + 0x8000u;
#if __has_builtin(__builtin_amdgcn_perm)
    return __builtin_amdgcn_perm(b, a, 0x07060302u);
#else
    return (a >> 16) | (b & 0xffff0000u);
#endif
}

__device__ __forceinline__ float fexp2(float x) {
#if __has_builtin(__builtin_amdgcn_exp2f)
    return __builtin_amdgcn_exp2f(x);
#else
    return exp2f(x);
#endif
}

// direct global->LDS DMA, 16B per lane; LDS dest = uniform base + lane*16
__device__ __forceinline__ void gll16(const unsigned short* g, unsigned short* l) {
    __builtin_amdgcn_global_load_lds(
        (const __attribute__((address_space(1))) unsigned int*)g,
        (__attribute__((address_space(3))) unsigned int*)l, 16, 0, 0);
}

// C/D-layout -> B-frag relayout (register-only transpose across quads)
__device__ __forceinline__ void pfr_quad_swap(unsigned &a, unsigned &b) {
#if __has_builtin(__builtin_amdgcn_permlane32_swap) && __has_builtin(__builtin_amdgcn_permlane16_swap)
    uint32x2 r0 = __builtin_amdgcn_permlane32_swap(a, b, false, false);
    uint32x2 r1 = __builtin_amdgcn_permlane16_swap(r0[0], r0[1], false, false);
    a = r1[0];
    b = r1[1];
#else
    const int lane = (int)(threadIdx.x & 63);
    const int li = lane & 15, quad = lane >> 4;
    const int s0 = (li + ((quad & 1) << 5)) << 2;
    const int s1 = (li + 16 + ((quad & 1) << 5)) << 2;
    int ra = __builtin_amdgcn_ds_bpermute(s0, (int)a);
    int rb = __builtin_amdgcn_ds_bpermute(s0, (int)b);
    int ta = __builtin_amdgcn_ds_bpermute(s1, (int)a);
    int tb = __builtin_amdgcn_ds_bpermute(s1, (int)b);
    const bool lo = quad < 2;
    a = (unsigned)(lo ? ra : rb);
    b = (unsigned)(lo ? ta : tb);
#endif
}

// ---------------------------------------------------------------------------
// Kernel 1: QKV projection with register-prefetch software pipeline.
// ---------------------------------------------------------------------------
__global__ __launch_bounds__(256) void qkv_proj_kernel(
    const float* __restrict__ x, const float* __restrict__ w,
    unsigned short* __restrict__ qb, unsigned short* __restrict__ kb,
    unsigned short* __restrict__ vb)
{
    __shared__ __align__(16) unsigned short XT[128 * 40];
    __shared__ __align__(16) unsigned short WT[128 * 40];
    const int tid = threadIdx.x;
    const int wave = tid >> 6, lane = tid & 63;
    const int quad = lane >> 4, li = lane & 15;
    const int o0 = blockIdx.x * 128, l0 = blockIdx.y * 128, b = blockIdx.z;

    const f32x4 fzero = {0.f, 0.f, 0.f, 0.f};
    f32x4 acc[2][8];
    #pragma unroll
    for (int mt = 0; mt < 2; mt++)
        #pragma unroll
        for (int nt = 0; nt < 8; nt++) acc[mt][nt] = fzero;

    const int xl = tid & 127, xg = tid >> 7;
    const int wcg = tid & 7, woo = tid >> 3;

    float xv[2][8];
    float4 wv[4];
    #pragma unroll
    for (int i = 0; i < 2; i++) {
        const int cch = xg + 2 * i;
        const float* xs = x + ((size_t)(b * NC + cch * 8)) * NL + l0 + xl;
        #pragma unroll
        for (int k = 0; k < 8; k++) xv[i][k] = xs[(size_t)k * NL];
    }
    #pragma unroll
    for (int rep = 0; rep < 4; rep++)
        wv[rep] = *(const float4*)&w[(size_t)(o0 + woo + rep * 32) * NC + wcg * 4];

    for (int c0 = 0; c0 < NC; c0 += 32) {
        #pragma unroll
        for (int i = 0; i < 2; i++) {
            const int cch = xg + 2 * i;
            unsigned p[4];
            #pragma unroll
            for (int k2 = 0; k2 < 4; k2++)
                p[k2] = (unsigned)f2bf(xv[i][2 * k2]) |
                        ((unsigned)f2bf(xv[i][2 * k2 + 1]) << 16);
            uint4 val; val.x = p[0]; val.y = p[1]; val.z = p[2]; val.w = p[3];
            *(uint4*)&XT[xl * 40 + cch * 8] = val;
        }
        #pragma unroll
        for (int rep = 0; rep < 4; rep++) {
            uint2 val;
            val.x = (unsigned)f2bf(wv[rep].x) | ((unsigned)f2bf(wv[rep].y) << 16);
            val.y = (unsigned)f2bf(wv[rep].z) | ((unsigned)f2bf(wv[rep].w) << 16);
            *(uint2*)&WT[(woo + rep * 32) * 40 + wcg * 4] = val;
        }
        __syncthreads();
        if (c0 + 32 < NC) {
            const int c1 = c0 + 32;
            #pragma unroll
            for (int i = 0; i < 2; i++) {
                const int cch = xg + 2 * i;
                const float* xs = x + ((size_t)(b * NC + c1 + cch * 8)) * NL + l0 + xl;
                #pragma unroll
                for (int k = 0; k < 8; k++) xv[i][k] = xs[(size_t)k * NL];
            }
            #pragma unroll
            for (int rep = 0; rep < 4; rep++)
                wv[rep] = *(const float4*)&w[(size_t)(o0 + woo + rep * 32) * NC + c1 + wcg * 4];
        }
        bf16x8 afr0 = *(const bf16x8*)&XT[(wave * 32 + li) * 40 + quad * 8];
        bf16x8 afr1 = *(const bf16x8*)&XT[(wave * 32 + 16 + li) * 40 + quad * 8];
        #pragma unroll
        for (int nt = 0; nt < 8; nt++) {
            bf16x8 bfr = *(const bf16x8*)&WT[(nt * 16 + li) * 40 + quad * 8];
            acc[0][nt] = __builtin_amdgcn_mfma_f32_16x16x32_bf16(afr0, bfr, acc[0][nt], 0, 0, 0);
            acc[1][nt] = __builtin_amdgcn_mfma_f32_16x16x32_bf16(afr1, bfr, acc[1][nt], 0, 0, 0);
        }
        __syncthreads();
    }

    const int lr0 = l0 + wave * 32;
    if (o0 < 1024) {
        unsigned short* dst = (o0 < 512) ? qb : kb;
        const float scale = (o0 < 512) ? (0.125f * 1.44269504088896f) : 1.0f;
        #pragma unroll
        for (int mt = 0; mt < 2; mt++)
            #pragma unroll
            for (int nt = 0; nt < 8; nt++) {
                int oc = (o0 & 511) + nt * 16 + li;
                int hh = oc >> 6, d = oc & 63;
                size_t base =
                    ((size_t)((b * NH + hh) * NL) + lr0 + mt * 16 + quad * 4) * ND + d;
                #pragma unroll
                for (int r = 0; r < 4; r++)
                    dst[base + (size_t)r * ND] = f2bf(acc[mt][nt][r] * scale);
            }
    } else {
        #pragma unroll
        for (int mt = 0; mt < 2; mt++)
            #pragma unroll
            for (int nt = 0; nt < 8; nt++) {
                int oc = (o0 - 1024) + nt * 16 + li;
                int hh = oc >> 6, d = oc & 63;
                size_t base = ((size_t)((b * NH + hh) * ND) + d) * NL +
                              lr0 + mt * 16 + quad * 4;
                uint2 pv;
                pv.x = (unsigned)f2bf(acc[mt][nt][0]) | ((unsigned)f2bf(acc[mt][nt][1]) << 16);
                pv.y = (unsigned)f2bf(acc[mt][nt][2]) | ((unsigned)f2bf(acc[mt][nt][3]) << 16);
                *(uint2*)&vb[base] = pv;
            }
    }
}

// ---------------------------------------------------------------------------
// Kernel 2: flash attention, global_load_lds staging (no VGPR round-trip,
// no ds_writes -> no staging spill, no staging bank conflicts).  Tiles are
// UNPADDED (gll requires lane-ordered contiguous LDS); bank conflicts on the
// read side are killed by an XOR swizzle applied to the per-lane GLOBAL
// address: Kt[j][c] = K[j][c ^ (j&7)] (16B chunks), Vt[d][c] = V[d][c ^ (d&15)].
// K reads land 2-way (free), V reads conflict-free.  Compute stays j-chunked
// (R6) to keep the live set small.  LDS 32KB.
// ---------------------------------------------------------------------------
__global__ __launch_bounds__(256) void attn_kernel(
    const unsigned short* __restrict__ qb, const unsigned short* __restrict__ kb,
    const unsigned short* __restrict__ vb, unsigned short* __restrict__ at)
{
    __shared__ __align__(16) unsigned short Kt[128 * 64];  // [j][d], swizzled
    __shared__ __align__(16) unsigned short Vt[64 * 128];  // [d][j], swizzled
    const int tid = threadIdx.x;
    const int wave = tid >> 6, lane = tid & 63;
    const int quad = lane >> 4, li = lane & 15;
    const int qt = blockIdx.x, h = blockIdx.y, b = blockIdx.z;
    const int bh = b * NH + h;
    const unsigned short* Qb = qb + (size_t)bh * NL * ND;
    const unsigned short* Kb = kb + (size_t)bh * NL * ND;
    const unsigned short* Vb = vb + (size_t)bh * ND * NL;

    bf16x8 qfr[2][2];
    #pragma unroll
    for (int mt = 0; mt < 2; mt++)
        #pragma unroll
        for (int kc = 0; kc < 2; kc++)
            qfr[mt][kc] = *(const bf16x8*)&Qb[(size_t)(qt * 128 + wave * 32 + mt * 16 + li) * ND +
                                             kc * 32 + quad * 8];

    const f32x4 fzero = {0.f, 0.f, 0.f, 0.f};
    float lsum0 = 0.f, lsum1 = 0.f;
    f32x4 oacc[2][4];
    #pragma unroll
    for (int mt = 0; mt < 2; mt++)
        #pragma unroll
        for (int dt = 0; dt < 4; dt++) oacc[mt][dt] = fzero;

    // staging decomposition: per wave-instr, 64 lanes x 16B = 1KB
    const int kj_loc = lane >> 3;   // K: 8 rows/instr
    const int kc8 = lane & 7;       // K: 8 chunks of 16B per 128B row
    const int vd_loc = lane >> 4;   // V: 4 rows/instr
    const int vc16 = lane & 15;     // V: 16 chunks of 16B per 256B row

    for (int kt = 0; kt < 16; kt++) {
        const int j0 = kt * 128;
        // stage K/V via direct-to-LDS DMA with swizzled global addresses
        #pragma unroll
        for (int i = 0; i < 4; i++) {
            const int jrow = wave * 32 + i * 8 + kj_loc;  // tile-local j
            gll16(Kb + (size_t)(j0 + jrow) * ND + ((kc8 ^ (jrow & 7)) * 8),
                  &Kt[(wave * 32 + i * 8) * ND]);
            const int drow = wave * 16 + i * 4 + vd_loc;  // d row
            gll16(Vb + (size_t)drow * NL + j0 + ((vc16 ^ (drow & 15)) * 8),
                  &Vt[(wave * 16 + i * 4) * 128]);
        }
        __syncthreads();  // drains vmcnt(0): gll data landed in LDS

        // process 4 chunks of 32 j-columns each: S^T -> exp2/pack -> PV
        #pragma unroll
        for (int c = 0; c < 4; c++) {
            f32x4 st00 = fzero, st01 = fzero, st10 = fzero, st11 = fzero;
            #pragma unroll
            for (int dk = 0; dk < 2; dk++) {
                const int sw = ((dk * 4 + quad) ^ (li & 7)) * 8;
                bf16x8 kf0 = *(const bf16x8*)&Kt[((2 * c + 0) * 16 + li) * ND + sw];
                bf16x8 kf1 = *(const bf16x8*)&Kt[((2 * c + 1) * 16 + li) * ND + sw];
                st00 = __builtin_amdgcn_mfma_f32_16x16x32_bf16(kf0, qfr[0][dk], st00, 0, 0, 0);
                st01 = __builtin_amdgcn_mfma_f32_16x16x32_bf16(kf1, qfr[0][dk], st01, 0, 0, 0);
                st10 = __builtin_amdgcn_mfma_f32_16x16x32_bf16(kf0, qfr[1][dk], st10, 0, 0, 0);
                st11 = __builtin_amdgcn_mfma_f32_16x16x32_bf16(kf1, qfr[1][dk], st11, 0, 0, 0);
            }

            unsigned p000, p001, p010, p011, p100, p101, p110, p111;
            {
                float a0 = fexp2(st00[0]), a1 = fexp2(st00[1]),
                      a2 = fexp2(st00[2]), a3 = fexp2(st00[3]);
                float b0 = fexp2(st01[0]), b1 = fexp2(st01[1]),
                      b2 = fexp2(st01[2]), b3 = fexp2(st01[3]);
                lsum0 += (a0 + a1) + (a2 + a3) + (b0 + b1) + (b2 + b3);
                p000 = pack_bf16_ru(a0, a1); p001 = pack_bf16_ru(a2, a3);
                p010 = pack_bf16_ru(b0, b1); p011 = pack_bf16_ru(b2, b3);
            }
            {
                float a0 = fexp2(st10[0]), a1 = fexp2(st10[1]),
                      a2 = fexp2(st10[2]), a3 = fexp2(st10[3]);
                float b0 = fexp2(st11[0]), b1 = fexp2(st11[1]),
                      b2 = fexp2(st11[2]), b3 = fexp2(st11[3]);
                lsum1 += (a0 + a1) + (a2 + a3) + (b0 + b1) + (b2 + b3);
                p100 = pack_bf16_ru(a0, a1); p101 = pack_bf16_ru(a2, a3);
                p110 = pack_bf16_ru(b0, b1); p111 = pack_bf16_ru(b2, b3);
            }

            pfr_quad_swap(p000, p010);
            pfr_quad_swap(p001, p011);
            pfr_quad_swap(p100, p110);
            pfr_quad_swap(p101, p111);

            uint32x4 u0 = {p000, p001, p010, p011};
            uint32x4 u1 = {p100, p101, p110, p111};
            bf16x8 pf0 = __builtin_bit_cast(bf16x8, u0);
            bf16x8 pf1 = __builtin_bit_cast(bf16x8, u1);

            #pragma unroll
            for (int dt = 0; dt < 4; dt++) {
                const int swv = (((c * 4 + quad) ^ li)) * 8;
                bf16x8 vfr = *(const bf16x8*)&Vt[(dt * 16 + li) * 128 + swv];
                oacc[0][dt] = __builtin_amdgcn_mfma_f32_16x16x32_bf16(vfr, pf0, oacc[0][dt], 0, 0, 0);
                oacc[1][dt] = __builtin_amdgcn_mfma_f32_16x16x32_bf16(vfr, pf1, oacc[1][dt], 0, 0, 0);
            }
        }
        __syncthreads();  // WAR: everyone done reading before next staging
    }

    lsum0 += __shfl_xor(lsum0, 16, 64);
    lsum0 += __shfl_xor(lsum0, 32, 64);
    lsum1 += __shfl_xor(lsum1, 16, 64);
    lsum1 += __shfl_xor(lsum1, 32, 64);

    #pragma unroll
    for (int mt = 0; mt < 2; mt++) {
        const float rl = 1.0f / (mt ? lsum1 : lsum0);
        const int l = qt * 128 + wave * 32 + mt * 16 + li;
        #pragma unroll
        for (int dt = 0; dt < 4; dt++) {
            uint2 ov;
            ov.x = (unsigned)f2bf(oacc[mt][dt][0] * rl) |
                   ((unsigned)f2bf(oacc[mt][dt][1] * rl) << 16);
            ov.y = (unsigned)f2bf(oacc[mt][dt][2] * rl) |
                   ((unsigned)f2bf(oacc[mt][dt][3] * rl) << 16);
            *(uint2*)&at[((size_t)(b * NL + l)) * NHID + h * ND + dt * 16 + quad * 4] = ov;
        }
    }
}

// ---------------------------------------------------------------------------
// Kernel 3: output projection with register-prefetch software pipeline.
// ---------------------------------------------------------------------------
__global__ __launch_bounds__(256) void out_proj_kernel(
    const unsigned short* __restrict__ at, const float* __restrict__ w,
    const float* __restrict__ bias, float* __restrict__ out)
{
    __shared__ __align__(16) unsigned short Wl[128 * 40];
    __shared__ __align__(16) unsigned short Al[128 * 40];
    const int tid = threadIdx.x;
    const int wave = tid >> 6, lane = tid & 63;
    const int quad = lane >> 4, li = lane & 15;
    const int o0 = blockIdx.x * 128, l0 = blockIdx.y * 128, b = blockIdx.z;

    const f32x4 fzero = {0.f, 0.f, 0.f, 0.f};
    f32x4 acc[2][8];
    #pragma unroll
    for (int mt = 0; mt < 2; mt++)
        #pragma unroll
        for (int nt = 0; nt < 8; nt++) acc[mt][nt] = fzero;

    const int wcg = tid & 7, woo = tid >> 3;
    const int ach = tid & 3, al0 = tid >> 2;

    float4 wv[4];
    uint4 av[2];
    #pragma unroll
    for (int rep = 0; rep < 4; rep++)
        wv[rep] = *(const float4*)&w[(size_t)(o0 + woo + rep * 32) * NHID + wcg * 4];
    #pragma unroll
    for (int rep = 0; rep < 2; rep++)
        av[rep] = *(const uint4*)&at[(size_t)(b * NL + l0 + al0 + rep * 64) * NHID + ach * 8];

    for (int c0 = 0; c0 < NHID; c0 += 32) {
        #pragma unroll
        for (int rep = 0; rep < 4; rep++) {
            uint2 val;
            val.x = (unsigned)f2bf(wv[rep].x) | ((unsigned)f2bf(wv[rep].y) << 16);
            val.y = (unsigned)f2bf(wv[rep].z) | ((unsigned)f2bf(wv[rep].w) << 16);
            *(uint2*)&Wl[(woo + rep * 32) * 40 + wcg * 4] = val;
        }
        #pragma unroll
        for (int rep = 0; rep < 2; rep++)
            *(uint4*)&Al[(al0 + rep * 64) * 40 + ach * 8] = av[rep];
        __syncthreads();
        if (c0 + 32 < NHID) {
            const int c1 = c0 + 32;
            #pragma unroll
            for (int rep = 0; rep < 4; rep++)
                wv[rep] = *(const float4*)&w[(size_t)(o0 + woo + rep * 32) * NHID + c1 + wcg * 4];
            #pragma unroll
            for (int rep = 0; rep < 2; rep++)
                av[rep] = *(const uint4*)&at[(size_t)(b * NL + l0 + al0 + rep * 64) * NHID + c1 + ach * 8];
        }
        bf16x8 afr0 = *(const bf16x8*)&Wl[(wave * 32 + li) * 40 + quad * 8];
        bf16x8 afr1 = *(const bf16x8*)&Wl[(wave * 32 + 16 + li) * 40 + quad * 8];
        #pragma unroll
        for (int nt = 0; nt < 8; nt++) {
            bf16x8 bfr = *(const bf16x8*)&Al[(nt * 16 + li) * 40 + quad * 8];
            acc[0][nt] = __builtin_amdgcn_mfma_f32_16x16x32_bf16(afr0, bfr, acc[0][nt], 0, 0, 0);
            acc[1][nt] = __builtin_amdgcn_mfma_f32_16x16x32_bf16(afr1, bfr, acc[1][nt], 0, 0, 0);
        }
        __syncthreads();
    }

    #pragma unroll
    for (int mt = 0; mt < 2; mt++) {
        int or0 = o0 + wave * 32 + mt * 16 + quad * 4;
        #pragma unroll
        for (int nt = 0; nt < 8; nt++) {
            int l = l0 + nt * 16 + li;
            #pragma unroll
            for (int r = 0; r < 4; r++)
                out[((size_t)(b * NC + or0 + r)) * NL + l] = acc[mt][nt][r] + bias[or0 + r];
        }
    }
}

extern "C" void kernel_launch(void* const* d_in, const int* in_sizes, int n_in,
                              void* d_out, int out_size, void* d_ws, size_t ws_size,
                              hipStream_t stream) {
    const float* x = (const float*)d_in[0];
    const float* w_qkv = (const float*)d_in[1];
    const float* w_out = (const float*)d_in[2];
    const float* b_out = (const float*)d_in[3];
    float* out = (float*)d_out;

    unsigned short* ws = (unsigned short*)d_ws;
    const size_t SZ = (size_t)NB * NH * NL * ND;
    unsigned short* qb = ws;
    unsigned short* kb = qb + SZ;
    unsigned short* vb = kb + SZ;
    unsigned short* at = vb + SZ;

    qkv_proj_kernel<<<dim3(12, 16, 8), dim3(256), 0, stream>>>(x, w_qkv, qb, kb, vb);
    attn_kernel<<<dim3(16, 8, 8), dim3(256), 0, stream>>>(qb, kb, vb, at);
    out_proj_kernel<<<dim3(4, 16, 8), dim3(256), 0, stream>>>(at, w_out, b_out, out);
}

// Round 8
// 245.150 us; speedup vs baseline: 1.6515x; 1.1068x over previous
//
#include <hip/hip_runtime.h>

#define NB 8
#define NC 512
#define NL 2048
#define NH 8
#define ND 64
#define NHID 512

typedef float f32x4 __attribute__((ext_vector_type(4)));
typedef short bf16x8 __attribute__((ext_vector_type(8)));
typedef unsigned uint32x2 __attribute__((ext_vector_type(2)));
typedef unsigned uint32x4 __attribute__((ext_vector_type(4)));

__device__ __forceinline__ unsigned short f2bf(float x) {
    unsigned u = __float_as_uint(x);
    u += 0x7fffu + ((u >> 16) & 1u);
    return (unsigned short)(u >> 16);
}

__device__ __forceinline__ unsigned pack_bf16_ru(float lo, float hi) {
    unsigned a = __float_as_uint(lo) + 0x8000u;
    unsigned b = __float_as_uint(hi) + 0x8000u;
#if __has_builtin(__builtin_amdgcn_perm)
    return __builtin_amdgcn_perm(b, a, 0x07060302u);
#else
    return (a >> 16) | (b & 0xffff0000u);
#endif
}

__device__ __forceinline__ float fexp2(float x) {
#if __has_builtin(__builtin_amdgcn_exp2f)
    return __builtin_amdgcn_exp2f(x);
#else
    return exp2f(x);
#endif
}

// direct global->LDS DMA, 16B per lane; LDS dest = uniform base + lane*16
__device__ __forceinline__ void gll16(const unsigned short* g, unsigned short* l) {
    __builtin_amdgcn_global_load_lds(
        (const __attribute__((address_space(1))) unsigned int*)g,
        (__attribute__((address_space(3))) unsigned int*)l, 16, 0, 0);
}

// C/D-layout -> B-frag relayout (register-only transpose across quads)
__device__ __forceinline__ void pfr_quad_swap(unsigned &a, unsigned &b) {
#if __has_builtin(__builtin_amdgcn_permlane32_swap) && __has_builtin(__builtin_amdgcn_permlane16_swap)
    uint32x2 r0 = __builtin_amdgcn_permlane32_swap(a, b, false, false);
    uint32x2 r1 = __builtin_amdgcn_permlane16_swap(r0[0], r0[1], false, false);
    a = r1[0];
    b = r1[1];
#else
    const int lane = (int)(threadIdx.x & 63);
    const int li = lane & 15, quad = lane >> 4;
    const int s0 = (li + ((quad & 1) << 5)) << 2;
    const int s1 = (li + 16 + ((quad & 1) << 5)) << 2;
    int ra = __builtin_amdgcn_ds_bpermute(s0, (int)a);
    int rb = __builtin_amdgcn_ds_bpermute(s0, (int)b);
    int ta = __builtin_amdgcn_ds_bpermute(s1, (int)a);
    int tb = __builtin_amdgcn_ds_bpermute(s1, (int)b);
    const bool lo = quad < 2;
    a = (unsigned)(lo ? ra : rb);
    b = (unsigned)(lo ? ta : tb);
#endif
}

// ---------------------------------------------------------------------------
// Prep A: transpose+convert x[b][c][l] fp32 -> xT[b][l][c] bf16.
// 64x64 tiles via LDS, stride-65 padding (conflict-free both phases).
// ---------------------------------------------------------------------------
__global__ __launch_bounds__(256) void xpose_kernel(
    const float* __restrict__ x, unsigned short* __restrict__ xT)
{
    __shared__ unsigned short T[64 * 65];
    const int tid = threadIdx.x;
    const int l0 = blockIdx.x * 64, c0 = blockIdx.y * 64, b = blockIdx.z;

    const int ll = tid & 63, cl0 = tid >> 6;
    #pragma unroll
    for (int i = 0; i < 16; i++) {
        const int cl = cl0 + 4 * i;
        T[cl * 65 + ll] = f2bf(x[((size_t)(b * NC + c0 + cl)) * NL + l0 + ll]);
    }
    __syncthreads();
    const int cg = tid & 7, lr = tid >> 3;
    #pragma unroll
    for (int rep = 0; rep < 2; rep++) {
        const int l = lr + rep * 32;
        unsigned u[4];
        #pragma unroll
        for (int j = 0; j < 4; j++) {
            unsigned short a = T[(cg * 8 + 2 * j) * 65 + l];
            unsigned short c = T[(cg * 8 + 2 * j + 1) * 65 + l];
            u[j] = (unsigned)a | ((unsigned)c << 16);
        }
        uint4 val; val.x = u[0]; val.y = u[1]; val.z = u[2]; val.w = u[3];
        *(uint4*)&xT[((size_t)(b * NL + l0 + l)) * NC + c0 + cg * 8] = val;
    }
}

// ---------------------------------------------------------------------------
// Prep B: fp32 -> bf16 weight conversion; first nscale8*8 elems scaled
// (folds Q's 0.125*log2e into w_qkv rows o<512).
// ---------------------------------------------------------------------------
__global__ __launch_bounds__(256) void wconv_kernel(
    const float* __restrict__ src, unsigned short* __restrict__ dst,
    int n8, int nscale8, float scale)
{
    const int idx = blockIdx.x * 256 + threadIdx.x;
    if (idx >= n8) return;
    const float s = (idx < nscale8) ? scale : 1.0f;
    float4 a = *(const float4*)&src[(size_t)idx * 8];
    float4 c = *(const float4*)&src[(size_t)idx * 8 + 4];
    uint4 val;
    val.x = (unsigned)f2bf(a.x * s) | ((unsigned)f2bf(a.y * s) << 16);
    val.y = (unsigned)f2bf(a.z * s) | ((unsigned)f2bf(a.w * s) << 16);
    val.z = (unsigned)f2bf(c.x * s) | ((unsigned)f2bf(c.y * s) << 16);
    val.w = (unsigned)f2bf(c.z * s) | ((unsigned)f2bf(c.w * s) << 16);
    *(uint4*)&dst[(size_t)idx * 8] = val;
}

// ---------------------------------------------------------------------------
// Kernel 1: QKV projection, attn-R7 skeleton: both operands bf16 k-contiguous
// in global (xT, wq_bf), staged via gll16 with XOR-chunk swizzle.  BK=64,
// 8 iters, 32 MFMA/iter.  Q-scale pre-folded into wq_bf rows o<512.
// ---------------------------------------------------------------------------
__global__ __launch_bounds__(256) void qkv_proj_kernel(
    const unsigned short* __restrict__ xT, const unsigned short* __restrict__ wq,
    unsigned short* __restrict__ qb, unsigned short* __restrict__ kb,
    unsigned short* __restrict__ vb)
{
    __shared__ __align__(16) unsigned short Xt[128 * 64];  // [l][c], swizzled
    __shared__ __align__(16) unsigned short Wt[128 * 64];  // [o][c], swizzled
    const int tid = threadIdx.x;
    const int wave = tid >> 6, lane = tid & 63;
    const int quad = lane >> 4, li = lane & 15;
    const int o0 = blockIdx.x * 128, l0 = blockIdx.y * 128, b = blockIdx.z;

    const f32x4 fzero = {0.f, 0.f, 0.f, 0.f};
    f32x4 acc[2][8];
    #pragma unroll
    for (int mt = 0; mt < 2; mt++)
        #pragma unroll
        for (int nt = 0; nt < 8; nt++) acc[mt][nt] = fzero;

    const int srow = lane >> 3, schk = lane & 7;

    for (int c0 = 0; c0 < NC; c0 += 64) {
        #pragma unroll
        for (int i = 0; i < 4; i++) {
            const int r = wave * 32 + i * 8 + srow;
            gll16(xT + ((size_t)(b * NL + l0 + r)) * NC + c0 + ((schk ^ (r & 7)) * 8),
                  &Xt[(wave * 32 + i * 8) * 64]);
            gll16(wq + (size_t)(o0 + r) * NC + c0 + ((schk ^ (r & 7)) * 8),
                  &Wt[(wave * 32 + i * 8) * 64]);
        }
        __syncthreads();
        #pragma unroll
        for (int kc = 0; kc < 2; kc++) {
            const int sw = ((kc * 4 + quad) ^ (li & 7)) * 8;
            bf16x8 afr0 = *(const bf16x8*)&Xt[(wave * 32 + li) * 64 + sw];
            bf16x8 afr1 = *(const bf16x8*)&Xt[(wave * 32 + 16 + li) * 64 + sw];
            #pragma unroll
            for (int nt = 0; nt < 8; nt++) {
                bf16x8 bfr = *(const bf16x8*)&Wt[(nt * 16 + li) * 64 + sw];
                acc[0][nt] = __builtin_amdgcn_mfma_f32_16x16x32_bf16(afr0, bfr, acc[0][nt], 0, 0, 0);
                acc[1][nt] = __builtin_amdgcn_mfma_f32_16x16x32_bf16(afr1, bfr, acc[1][nt], 0, 0, 0);
            }
        }
        __syncthreads();
    }

    // Epilogue.  C/D: row(m=l)=quad*4+reg, col(n=o)=li.  Scale pre-folded.
    const int lr0 = l0 + wave * 32;
    if (o0 < 1024) {
        unsigned short* dst = (o0 < 512) ? qb : kb;
        #pragma unroll
        for (int mt = 0; mt < 2; mt++)
            #pragma unroll
            for (int nt = 0; nt < 8; nt++) {
                int oc = (o0 & 511) + nt * 16 + li;
                int hh = oc >> 6, d = oc & 63;
                size_t base =
                    ((size_t)((b * NH + hh) * NL) + lr0 + mt * 16 + quad * 4) * ND + d;
                #pragma unroll
                for (int r = 0; r < 4; r++)
                    dst[base + (size_t)r * ND] = f2bf(acc[mt][nt][r]);
            }
    } else {
        #pragma unroll
        for (int mt = 0; mt < 2; mt++)
            #pragma unroll
            for (int nt = 0; nt < 8; nt++) {
                int oc = (o0 - 1024) + nt * 16 + li;
                int hh = oc >> 6, d = oc & 63;
                size_t base = ((size_t)((b * NH + hh) * ND) + d) * NL +
                              lr0 + mt * 16 + quad * 4;
                uint2 pv;
                pv.x = (unsigned)f2bf(acc[mt][nt][0]) | ((unsigned)f2bf(acc[mt][nt][1]) << 16);
                pv.y = (unsigned)f2bf(acc[mt][nt][2]) | ((unsigned)f2bf(acc[mt][nt][3]) << 16);
                *(uint2*)&vb[base] = pv;
            }
    }
}

// ---------------------------------------------------------------------------
// Kernel 2: flash attention (unchanged from R7: gll16 staging, swizzled
// unpadded tiles, j-chunked fixed-base softmax, permlane P-relayout).
// ---------------------------------------------------------------------------
__global__ __launch_bounds__(256) void attn_kernel(
    const unsigned short* __restrict__ qb, const unsigned short* __restrict__ kb,
    const unsigned short* __restrict__ vb, unsigned short* __restrict__ at)
{
    __shared__ __align__(16) unsigned short Kt[128 * 64];  // [j][d], swizzled
    __shared__ __align__(16) unsigned short Vt[64 * 128];  // [d][j], swizzled
    const int tid = threadIdx.x;
    const int wave = tid >> 6, lane = tid & 63;
    const int quad = lane >> 4, li = lane & 15;
    const int qt = blockIdx.x, h = blockIdx.y, b = blockIdx.z;
    const int bh = b * NH + h;
    const unsigned short* Qb = qb + (size_t)bh * NL * ND;
    const unsigned short* Kb = kb + (size_t)bh * NL * ND;
    const unsigned short* Vb = vb + (size_t)bh * ND * NL;

    bf16x8 qfr[2][2];
    #pragma unroll
    for (int mt = 0; mt < 2; mt++)
        #pragma unroll
        for (int kc = 0; kc < 2; kc++)
            qfr[mt][kc] = *(const bf16x8*)&Qb[(size_t)(qt * 128 + wave * 32 + mt * 16 + li) * ND +
                                             kc * 32 + quad * 8];

    const f32x4 fzero = {0.f, 0.f, 0.f, 0.f};
    float lsum0 = 0.f, lsum1 = 0.f;
    f32x4 oacc[2][4];
    #pragma unroll
    for (int mt = 0; mt < 2; mt++)
        #pragma unroll
        for (int dt = 0; dt < 4; dt++) oacc[mt][dt] = fzero;

    const int kj_loc = lane >> 3;
    const int kc8 = lane & 7;
    const int vd_loc = lane >> 4;
    const int vc16 = lane & 15;

    for (int kt = 0; kt < 16; kt++) {
        const int j0 = kt * 128;
        #pragma unroll
        for (int i = 0; i < 4; i++) {
            const int jrow = wave * 32 + i * 8 + kj_loc;
            gll16(Kb + (size_t)(j0 + jrow) * ND + ((kc8 ^ (jrow & 7)) * 8),
                  &Kt[(wave * 32 + i * 8) * ND]);
            const int drow = wave * 16 + i * 4 + vd_loc;
            gll16(Vb + (size_t)drow * NL + j0 + ((vc16 ^ (drow & 15)) * 8),
                  &Vt[(wave * 16 + i * 4) * 128]);
        }
        __syncthreads();

        #pragma unroll
        for (int c = 0; c < 4; c++) {
            f32x4 st00 = fzero, st01 = fzero, st10 = fzero, st11 = fzero;
            #pragma unroll
            for (int dk = 0; dk < 2; dk++) {
                const int sw = ((dk * 4 + quad) ^ (li & 7)) * 8;
                bf16x8 kf0 = *(const bf16x8*)&Kt[((2 * c + 0) * 16 + li) * ND + sw];
                bf16x8 kf1 = *(const bf16x8*)&Kt[((2 * c + 1) * 16 + li) * ND + sw];
                st00 = __builtin_amdgcn_mfma_f32_16x16x32_bf16(kf0, qfr[0][dk], st00, 0, 0, 0);
                st01 = __builtin_amdgcn_mfma_f32_16x16x32_bf16(kf1, qfr[0][dk], st01, 0, 0, 0);
                st10 = __builtin_amdgcn_mfma_f32_16x16x32_bf16(kf0, qfr[1][dk], st10, 0, 0, 0);
                st11 = __builtin_amdgcn_mfma_f32_16x16x32_bf16(kf1, qfr[1][dk], st11, 0, 0, 0);
            }

            unsigned p000, p001, p010, p011, p100, p101, p110, p111;
            {
                float a0 = fexp2(st00[0]), a1 = fexp2(st00[1]),
                      a2 = fexp2(st00[2]), a3 = fexp2(st00[3]);
                float b0 = fexp2(st01[0]), b1 = fexp2(st01[1]),
                      b2 = fexp2(st01[2]), b3 = fexp2(st01[3]);
                lsum0 += (a0 + a1) + (a2 + a3) + (b0 + b1) + (b2 + b3);
                p000 = pack_bf16_ru(a0, a1); p001 = pack_bf16_ru(a2, a3);
                p010 = pack_bf16_ru(b0, b1); p011 = pack_bf16_ru(b2, b3);
            }
            {
                float a0 = fexp2(st10[0]), a1 = fexp2(st10[1]),
                      a2 = fexp2(st10[2]), a3 = fexp2(st10[3]);
                float b0 = fexp2(st11[0]), b1 = fexp2(st11[1]),
                      b2 = fexp2(st11[2]), b3 = fexp2(st11[3]);
                lsum1 += (a0 + a1) + (a2 + a3) + (b0 + b1) + (b2 + b3);
                p100 = pack_bf16_ru(a0, a1); p101 = pack_bf16_ru(a2, a3);
                p110 = pack_bf16_ru(b0, b1); p111 = pack_bf16_ru(b2, b3);
            }

            pfr_quad_swap(p000, p010);
            pfr_quad_swap(p001, p011);
            pfr_quad_swap(p100, p110);
            pfr_quad_swap(p101, p111);

            uint32x4 u0 = {p000, p001, p010, p011};
            uint32x4 u1 = {p100, p101, p110, p111};
            bf16x8 pf0 = __builtin_bit_cast(bf16x8, u0);
            bf16x8 pf1 = __builtin_bit_cast(bf16x8, u1);

            #pragma unroll
            for (int dt = 0; dt < 4; dt++) {
                const int swv = (((c * 4 + quad) ^ li)) * 8;
                bf16x8 vfr = *(const bf16x8*)&Vt[(dt * 16 + li) * 128 + swv];
                oacc[0][dt] = __builtin_amdgcn_mfma_f32_16x16x32_bf16(vfr, pf0, oacc[0][dt], 0, 0, 0);
                oacc[1][dt] = __builtin_amdgcn_mfma_f32_16x16x32_bf16(vfr, pf1, oacc[1][dt], 0, 0, 0);
            }
        }
        __syncthreads();
    }

    lsum0 += __shfl_xor(lsum0, 16, 64);
    lsum0 += __shfl_xor(lsum0, 32, 64);
    lsum1 += __shfl_xor(lsum1, 16, 64);
    lsum1 += __shfl_xor(lsum1, 32, 64);

    #pragma unroll
    for (int mt = 0; mt < 2; mt++) {
        const float rl = 1.0f / (mt ? lsum1 : lsum0);
        const int l = qt * 128 + wave * 32 + mt * 16 + li;
        #pragma unroll
        for (int dt = 0; dt < 4; dt++) {
            uint2 ov;
            ov.x = (unsigned)f2bf(oacc[mt][dt][0] * rl) |
                   ((unsigned)f2bf(oacc[mt][dt][1] * rl) << 16);
            ov.y = (unsigned)f2bf(oacc[mt][dt][2] * rl) |
                   ((unsigned)f2bf(oacc[mt][dt][3] * rl) << 16);
            *(uint2*)&at[((size_t)(b * NL + l)) * NHID + h * ND + dt * 16 + quad * 4] = ov;
        }
    }
}

// ---------------------------------------------------------------------------
// Kernel 3: output projection, attn-R7 skeleton (gll16 + swizzle, BK=64).
// A = wo_bf[o][c] (m=o), B = at[b][l][c] (n=l); C row=o, col=l.
// ---------------------------------------------------------------------------
__global__ __launch_bounds__(256) void out_proj_kernel(
    const unsigned short* __restrict__ at, const unsigned short* __restrict__ wo,
    const float* __restrict__ bias, float* __restrict__ out)
{
    __shared__ __align__(16) unsigned short Wt[128 * 64];  // [o][c], swizzled
    __shared__ __align__(16) unsigned short At[128 * 64];  // [l][c], swizzled
    const int tid = threadIdx.x;
    const int wave = tid >> 6, lane = tid & 63;
    const int quad = lane >> 4, li = lane & 15;
    const int o0 = blockIdx.x * 128, l0 = blockIdx.y * 128, b = blockIdx.z;

    const f32x4 fzero = {0.f, 0.f, 0.f, 0.f};
    f32x4 acc[2][8];
    #pragma unroll
    for (int mt = 0; mt < 2; mt++)
        #pragma unroll
        for (int nt = 0; nt < 8; nt++) acc[mt][nt] = fzero;

    const int srow = lane >> 3, schk = lane & 7;

    for (int c0 = 0; c0 < NHID; c0 += 64) {
        #pragma unroll
        for (int i = 0; i < 4; i++) {
            const int r = wave * 32 + i * 8 + srow;
            gll16(wo + (size_t)(o0 + r) * NHID + c0 + ((schk ^ (r & 7)) * 8),
                  &Wt[(wave * 32 + i * 8) * 64]);
            gll16(at + ((size_t)(b * NL + l0 + r)) * NHID + c0 + ((schk ^ (r & 7)) * 8),
                  &At[(wave * 32 + i * 8) * 64]);
        }
        __syncthreads();
        #pragma unroll
        for (int kc = 0; kc < 2; kc++) {
            const int sw = ((kc * 4 + quad) ^ (li & 7)) * 8;
            bf16x8 afr0 = *(const bf16x8*)&Wt[(wave * 32 + li) * 64 + sw];
            bf16x8 afr1 = *(const bf16x8*)&Wt[(wave * 32 + 16 + li) * 64 + sw];
            #pragma unroll
            for (int nt = 0; nt < 8; nt++) {
                bf16x8 bfr = *(const bf16x8*)&At[(nt * 16 + li) * 64 + sw];
                acc[0][nt] = __builtin_amdgcn_mfma_f32_16x16x32_bf16(afr0, bfr, acc[0][nt], 0, 0, 0);
                acc[1][nt] = __builtin_amdgcn_mfma_f32_16x16x32_bf16(afr1, bfr, acc[1][nt], 0, 0, 0);
            }
        }
        __syncthreads();
    }

    #pragma unroll
    for (int mt = 0; mt < 2; mt++) {
        int or0 = o0 + wave * 32 + mt * 16 + quad * 4;
        #pragma unroll
        for (int nt = 0; nt < 8; nt++) {
            int l = l0 + nt * 16 + li;
            #pragma unroll
            for (int r = 0; r < 4; r++)
                out[((size_t)(b * NC + or0 + r)) * NL + l] = acc[mt][nt][r] + bias[or0 + r];
        }
    }
}

extern "C" void kernel_launch(void* const* d_in, const int* in_sizes, int n_in,
                              void* d_out, int out_size, void* d_ws, size_t ws_size,
                              hipStream_t stream) {
    const float* x = (const float*)d_in[0];
    const float* w_qkv = (const float*)d_in[1];
    const float* w_out = (const float*)d_in[2];
    const float* b_out = (const float*)d_in[3];
    float* out = (float*)d_out;

    unsigned short* ws = (unsigned short*)d_ws;
    const size_t SZ = (size_t)NB * NH * NL * ND;      // 8.39M elems
    unsigned short* qb = ws;
    unsigned short* kb = qb + SZ;
    unsigned short* vb = kb + SZ;
    unsigned short* at = vb + SZ;
    unsigned short* xT = at + SZ;                     // NB*NL*NC == SZ
    unsigned short* wqb = xT + SZ;
    unsigned short* wob = wqb + (size_t)3 * NHID * NC;

    // prep: transpose+convert X; convert weights (Q-scale folded)
    xpose_kernel<<<dim3(NL / 64, NC / 64, NB), dim3(256), 0, stream>>>(x, xT);
    wconv_kernel<<<dim3((3 * NHID * NC / 8 + 255) / 256), dim3(256), 0, stream>>>(
        w_qkv, wqb, 3 * NHID * NC / 8, NHID * NC / 8, 0.125f * 1.44269504088896f);
    wconv_kernel<<<dim3((NC * NHID / 8 + 255) / 256), dim3(256), 0, stream>>>(
        w_out, wob, NC * NHID / 8, 0, 1.0f);

    qkv_proj_kernel<<<dim3(12, 16, 8), dim3(256), 0, stream>>>(xT, wqb, qb, kb, vb);
    attn_kernel<<<dim3(16, 8, 8), dim3(256), 0, stream>>>(qb, kb, vb, at);
    out_proj_kernel<<<dim3(4, 16, 8), dim3(256), 0, stream>>>(at, wob, b_out, out);
}